// Round 2
// baseline (236.952 us; speedup 1.0000x reference)
//
#include <hip/hip_runtime.h>
#include <hip/hip_bf16.h>

#define Sx 256
#define Dx 300
#define Mx 1024          // B*S
#define CCONST 5.0f

__device__ __forceinline__ float bf2f(unsigned short u) {
    union { unsigned int i; float f; } v;
    v.i = ((unsigned int)u) << 16;
    return v.f;
}

__device__ __forceinline__ float fast_tanh(float x) {
    float e = __expf(2.0f * x);
    return (e - 1.0f) / (e + 1.0f);
}

// Detect whether a float-weight array (values ~N(0,0.05)) is stored as bf16.
// bf16: first 64 bf16-interps all |v|<1 (certain). fp32 misread as bf16:
// ~32 random-exponent low-halves -> P(all<1) ~ 2e-10.
__device__ __forceinline__ int detect_bf16(const void* w) {
    const unsigned short* u = (const unsigned short*)w;
    int ok = 1;
    #pragma unroll
    for (int t = 0; t < 64; ++t) {
        float v = bf2f(u[t]);
        ok &= (fabsf(v) < 1.0f) ? 1 : 0;   // NaN/inf also fail -> fp32
    }
    return ok;
}

__device__ __forceinline__ float load_scalar(const void* p, int idx, int isbf) {
    return isbf ? bf2f(((const unsigned short*)p)[idx]) : ((const float*)p)[idx];
}

// ---------------------------------------------------------------------------
// Kernel 1: rep_map = elu(X @ W_fc^T + b_fc) -> fp32 ws
// ---------------------------------------------------------------------------
__global__ __launch_bounds__(320) void k_repmap(
        const void* __restrict__ Xv, const void* __restrict__ Wv,
        const void* __restrict__ bv, float* __restrict__ out) {
    __shared__ __align__(16) float Xs[4][304];
    __shared__ int s_isbf;
    const int tid = threadIdx.x;
    const int m0 = blockIdx.x * 4;
    if (tid == 0) s_isbf = detect_bf16(Wv);
    __syncthreads();
    const int isbf = s_isbf;
    if (isbf) {
        const unsigned short* X = (const unsigned short*)Xv;
        for (int idx = tid; idx < 4 * Dx; idx += 320) {
            int r = idx / Dx, c = idx - r * Dx;
            Xs[r][c] = bf2f(X[m0 * Dx + idx]);
        }
    } else {
        const float* X = (const float*)Xv;
        for (int idx = tid; idx < 4 * Dx; idx += 320) {
            int r = idx / Dx, c = idx - r * Dx;
            Xs[r][c] = X[m0 * Dx + idx];
        }
    }
    __syncthreads();
    const int g = tid;
    if (g < Dx) {
        float a0 = 0.f, a1 = 0.f, a2 = 0.f, a3 = 0.f;
        if (isbf) {
            const unsigned short* wr = (const unsigned short*)Wv + g * Dx;
            for (int k = 0; k < Dx; k += 4) {
                ushort4 wv = *(const ushort4*)(wr + k);
                float w0 = bf2f(wv.x), w1 = bf2f(wv.y), w2 = bf2f(wv.z), w3 = bf2f(wv.w);
                float4 x0 = *(const float4*)(&Xs[0][k]);
                float4 x1 = *(const float4*)(&Xs[1][k]);
                float4 x2 = *(const float4*)(&Xs[2][k]);
                float4 x3 = *(const float4*)(&Xs[3][k]);
                a0 += x0.x * w0 + x0.y * w1 + x0.z * w2 + x0.w * w3;
                a1 += x1.x * w0 + x1.y * w1 + x1.z * w2 + x1.w * w3;
                a2 += x2.x * w0 + x2.y * w1 + x2.z * w2 + x2.w * w3;
                a3 += x3.x * w0 + x3.y * w1 + x3.z * w2 + x3.w * w3;
            }
        } else {
            const float* wr = (const float*)Wv + g * Dx;
            for (int k = 0; k < Dx; k += 4) {
                float4 wv = *(const float4*)(wr + k);
                float4 x0 = *(const float4*)(&Xs[0][k]);
                float4 x1 = *(const float4*)(&Xs[1][k]);
                float4 x2 = *(const float4*)(&Xs[2][k]);
                float4 x3 = *(const float4*)(&Xs[3][k]);
                a0 += x0.x * wv.x + x0.y * wv.y + x0.z * wv.z + x0.w * wv.w;
                a1 += x1.x * wv.x + x1.y * wv.y + x1.z * wv.z + x1.w * wv.w;
                a2 += x2.x * wv.x + x2.y * wv.y + x2.z * wv.z + x2.w * wv.w;
                a3 += x3.x * wv.x + x3.y * wv.y + x3.z * wv.z + x3.w * wv.w;
            }
        }
        float bb = load_scalar(bv, g, isbf);
        float acc[4] = {a0, a1, a2, a3};
        #pragma unroll
        for (int r = 0; r < 4; ++r) {
            float v = acc[r] + bb;
            v = v > 0.f ? v : (__expf(v) - 1.0f);   // elu
            out[(m0 + r) * Dx + g] = v;
        }
    }
}

// ---------------------------------------------------------------------------
// Kernel 2: dep = rep @ W1^T + b1 ; head = rep @ W2^T (fused N=600)
// ---------------------------------------------------------------------------
__global__ __launch_bounds__(640) void k_dephead(
        const float* __restrict__ Xin,
        const void* __restrict__ W1v, const void* __restrict__ W2v,
        const void* __restrict__ b1v,
        float* __restrict__ dep, float* __restrict__ head) {
    __shared__ __align__(16) float Xs[4][304];
    __shared__ int s_isbf;
    const int tid = threadIdx.x;
    const int m0 = blockIdx.x * 4;
    if (tid == 0) s_isbf = detect_bf16(W1v);
    for (int idx = tid; idx < 4 * Dx; idx += 640) {
        int r = idx / Dx, c = idx - r * Dx;
        Xs[r][c] = Xin[m0 * Dx + idx];
    }
    __syncthreads();
    const int isbf = s_isbf;
    const int g = tid;
    if (g < 2 * Dx) {
        float a0 = 0.f, a1 = 0.f, a2 = 0.f, a3 = 0.f;
        if (isbf) {
            const unsigned short* wr = (g < Dx)
                ? ((const unsigned short*)W1v + g * Dx)
                : ((const unsigned short*)W2v + (g - Dx) * Dx);
            for (int k = 0; k < Dx; k += 4) {
                ushort4 wv = *(const ushort4*)(wr + k);
                float w0 = bf2f(wv.x), w1 = bf2f(wv.y), w2 = bf2f(wv.z), w3 = bf2f(wv.w);
                float4 x0 = *(const float4*)(&Xs[0][k]);
                float4 x1 = *(const float4*)(&Xs[1][k]);
                float4 x2 = *(const float4*)(&Xs[2][k]);
                float4 x3 = *(const float4*)(&Xs[3][k]);
                a0 += x0.x * w0 + x0.y * w1 + x0.z * w2 + x0.w * w3;
                a1 += x1.x * w0 + x1.y * w1 + x1.z * w2 + x1.w * w3;
                a2 += x2.x * w0 + x2.y * w1 + x2.z * w2 + x2.w * w3;
                a3 += x3.x * w0 + x3.y * w1 + x3.z * w2 + x3.w * w3;
            }
        } else {
            const float* wr = (g < Dx)
                ? ((const float*)W1v + g * Dx)
                : ((const float*)W2v + (g - Dx) * Dx);
            for (int k = 0; k < Dx; k += 4) {
                float4 wv = *(const float4*)(wr + k);
                float4 x0 = *(const float4*)(&Xs[0][k]);
                float4 x1 = *(const float4*)(&Xs[1][k]);
                float4 x2 = *(const float4*)(&Xs[2][k]);
                float4 x3 = *(const float4*)(&Xs[3][k]);
                a0 += x0.x * wv.x + x0.y * wv.y + x0.z * wv.z + x0.w * wv.w;
                a1 += x1.x * wv.x + x1.y * wv.y + x1.z * wv.z + x1.w * wv.w;
                a2 += x2.x * wv.x + x2.y * wv.y + x2.z * wv.z + x2.w * wv.w;
                a3 += x3.x * wv.x + x3.y * wv.y + x3.z * wv.z + x3.w * wv.w;
            }
        }
        float acc[4] = {a0, a1, a2, a3};
        if (g < Dx) {
            float bb = load_scalar(b1v, g, isbf);   // fold b1 into dep
            #pragma unroll
            for (int r = 0; r < 4; ++r) dep[(m0 + r) * Dx + g] = acc[r] + bb;
        } else {
            const int gg = g - Dx;
            #pragma unroll
            for (int r = 0; r < 4; ++r) head[(m0 + r) * Dx + gg] = acc[r];
        }
    }
}

// ---------------------------------------------------------------------------
// Kernel 3: fused per-feature masked causal softmax + weighted sum (fp32 ws)
// m = max(0, C*tanh(max_valid_arg/C)) — 0 from masked entries in ref's max.
// ---------------------------------------------------------------------------
__global__ __launch_bounds__(320) void k_attn(
        const float* __restrict__ dep,
        const float* __restrict__ head,
        const float* __restrict__ rep,
        const int* __restrict__ mask,
        float* __restrict__ attn) {
    const int m = blockIdx.x;
    const int b = m >> 8, i = m & 255;
    const int d = threadIdx.x;
    if (d >= Dx) return;
    const float hv = head[m * Dx + d];
    const int base = b * Sx;

    float amax = -1e30f;
    for (int j = i + 1; j < Sx; ++j) {
        if (mask[base + j]) amax = fmaxf(amax, dep[(base + j) * Dx + d]);
    }
    const float lm = CCONST * fast_tanh((amax + hv) * (1.0f / CCONST));
    const float mval = fmaxf(0.0f, lm);

    float s = 0.f, r = 0.f;
    for (int j = i + 1; j < Sx; ++j) {
        if (mask[base + j]) {
            float a = dep[(base + j) * Dx + d] + hv;
            float l = CCONST * fast_tanh(a * (1.0f / CCONST));
            float e = __expf(l - mval);
            s += e;
            r += e * rep[(base + j) * Dx + d];
        }
    }
    const float denom = s + (s == 0.0f ? 1.0f : 0.0f) + 1e-20f;
    attn[m * Dx + d] = r / denom;
}

// ---------------------------------------------------------------------------
// Kernel 4: gate = sigmoid([rep|attn] @ [W_f1|W_f2]^T + b_f);
//           out = (gate*rep + (1-gate)*attn) * rep_mask
// ---------------------------------------------------------------------------
__global__ __launch_bounds__(320) void k_gate(
        const float* __restrict__ rep,
        const float* __restrict__ attn,
        const void* __restrict__ W1v, const void* __restrict__ W2v,
        const void* __restrict__ bv,
        const int* __restrict__ mask,
        void* __restrict__ outv) {
    __shared__ __align__(16) float Xs[4][608];   // [0..299]=rep, [300..599]=attn
    __shared__ int s_isbf;
    const int tid = threadIdx.x;
    const int m0 = blockIdx.x * 4;
    if (tid == 0) s_isbf = detect_bf16(W1v);
    for (int idx = tid; idx < 4 * Dx; idx += 320) {
        int r = idx / Dx, c = idx - r * Dx;
        Xs[r][c]      = rep[m0 * Dx + idx];
        Xs[r][Dx + c] = attn[m0 * Dx + idx];
    }
    __syncthreads();
    const int isbf = s_isbf;
    const int g = tid;
    if (g < Dx) {
        float a0 = 0.f, a1 = 0.f, a2 = 0.f, a3 = 0.f;
        if (isbf) {
            const unsigned short* w1r = (const unsigned short*)W1v + g * Dx;
            const unsigned short* w2r = (const unsigned short*)W2v + g * Dx;
            for (int k = 0; k < Dx; k += 4) {
                ushort4 wv = *(const ushort4*)(w1r + k);
                float w0 = bf2f(wv.x), w1 = bf2f(wv.y), w2 = bf2f(wv.z), w3 = bf2f(wv.w);
                float4 x0 = *(const float4*)(&Xs[0][k]);
                float4 x1 = *(const float4*)(&Xs[1][k]);
                float4 x2 = *(const float4*)(&Xs[2][k]);
                float4 x3 = *(const float4*)(&Xs[3][k]);
                a0 += x0.x * w0 + x0.y * w1 + x0.z * w2 + x0.w * w3;
                a1 += x1.x * w0 + x1.y * w1 + x1.z * w2 + x1.w * w3;
                a2 += x2.x * w0 + x2.y * w1 + x2.z * w2 + x2.w * w3;
                a3 += x3.x * w0 + x3.y * w1 + x3.z * w2 + x3.w * w3;
            }
            for (int k = 0; k < Dx; k += 4) {
                ushort4 wv = *(const ushort4*)(w2r + k);
                float w0 = bf2f(wv.x), w1 = bf2f(wv.y), w2 = bf2f(wv.z), w3 = bf2f(wv.w);
                float4 x0 = *(const float4*)(&Xs[0][Dx + k]);
                float4 x1 = *(const float4*)(&Xs[1][Dx + k]);
                float4 x2 = *(const float4*)(&Xs[2][Dx + k]);
                float4 x3 = *(const float4*)(&Xs[3][Dx + k]);
                a0 += x0.x * w0 + x0.y * w1 + x0.z * w2 + x0.w * w3;
                a1 += x1.x * w0 + x1.y * w1 + x1.z * w2 + x1.w * w3;
                a2 += x2.x * w0 + x2.y * w1 + x2.z * w2 + x2.w * w3;
                a3 += x3.x * w0 + x3.y * w1 + x3.z * w2 + x3.w * w3;
            }
        } else {
            const float* w1r = (const float*)W1v + g * Dx;
            const float* w2r = (const float*)W2v + g * Dx;
            for (int k = 0; k < Dx; k += 4) {
                float4 wv = *(const float4*)(w1r + k);
                float4 x0 = *(const float4*)(&Xs[0][k]);
                float4 x1 = *(const float4*)(&Xs[1][k]);
                float4 x2 = *(const float4*)(&Xs[2][k]);
                float4 x3 = *(const float4*)(&Xs[3][k]);
                a0 += x0.x * wv.x + x0.y * wv.y + x0.z * wv.z + x0.w * wv.w;
                a1 += x1.x * wv.x + x1.y * wv.y + x1.z * wv.z + x1.w * wv.w;
                a2 += x2.x * wv.x + x2.y * wv.y + x2.z * wv.z + x2.w * wv.w;
                a3 += x3.x * wv.x + x3.y * wv.y + x3.z * wv.z + x3.w * wv.w;
            }
            for (int k = 0; k < Dx; k += 4) {
                float4 wv = *(const float4*)(w2r + k);
                float4 x0 = *(const float4*)(&Xs[0][Dx + k]);
                float4 x1 = *(const float4*)(&Xs[1][Dx + k]);
                float4 x2 = *(const float4*)(&Xs[2][Dx + k]);
                float4 x3 = *(const float4*)(&Xs[3][Dx + k]);
                a0 += x0.x * wv.x + x0.y * wv.y + x0.z * wv.z + x0.w * wv.w;
                a1 += x1.x * wv.x + x1.y * wv.y + x1.z * wv.z + x1.w * wv.w;
                a2 += x2.x * wv.x + x2.y * wv.y + x2.z * wv.z + x2.w * wv.w;
                a3 += x3.x * wv.x + x3.y * wv.y + x3.z * wv.z + x3.w * wv.w;
            }
        }
        float bb = load_scalar(bv, g, isbf);
        float acc[4] = {a0, a1, a2, a3};
        #pragma unroll
        for (int r = 0; r < 4; ++r) {
            float gp = acc[r] + bb;
            float gate = 1.0f / (1.0f + __expf(-gp));
            float rv = Xs[r][g];
            float av = Xs[r][Dx + g];
            float res = (gate * rv + (1.0f - gate) * av) * (float)mask[m0 + r];
            if (isbf) ((__hip_bfloat16*)outv)[(m0 + r) * Dx + g] = __float2bfloat16(res);
            else      ((float*)outv)[(m0 + r) * Dx + g] = res;
        }
    }
}

extern "C" void kernel_launch(void* const* d_in, const int* in_sizes, int n_in,
                              void* d_out, int out_size, void* d_ws, size_t ws_size,
                              hipStream_t stream) {
    const void* X   = d_in[0];
    const int*  msk = (const int*)d_in[1];
    const void* Wfc = d_in[2];
    const void* bfc = d_in[3];
    const void* W1  = d_in[4];
    const void* W2  = d_in[5];
    const void* b1  = d_in[6];
    const void* Wf1 = d_in[7];
    const void* Wf2 = d_in[8];
    const void* bfv = d_in[9];

    float* rep  = (float*)d_ws;          // [1024,300] fp32
    float* dep  = rep  + Mx * Dx;
    float* head = dep  + Mx * Dx;
    float* attn = head + Mx * Dx;

    hipLaunchKernelGGL(k_repmap,  dim3(Mx / 4), dim3(320), 0, stream, X, Wfc, bfc, rep);
    hipLaunchKernelGGL(k_dephead, dim3(Mx / 4), dim3(640), 0, stream, rep, W1, W2, b1, dep, head);
    hipLaunchKernelGGL(k_attn,    dim3(Mx),     dim3(320), 0, stream, dep, head, rep, msk, attn);
    hipLaunchKernelGGL(k_gate,    dim3(Mx / 4), dim3(320), 0, stream, rep, attn, Wf1, Wf2, bfv, msk, d_out);
}